// Round 17
// baseline (3555.720 us; speedup 1.0000x reference)
//
#include <hip/hip_runtime.h>
#include <hip/hip_fp16.h>
#include <math.h>

// resRNN forward: N=256, L=1024, inp=521 (=8 x + 1 storage + 512 hx), HID=512, OUT=1.
// Round 17: R16 + FULL W1 residency. R16's counters showed VGPR_Count=64 of a
// 128 budget -- half the register file idle while we paid 3.4K cyc/step
// streaming 131 KB from L2. The streamed pairs move into 36 pinned ARCH VGPRs
// per thread (same pk2h_rne packing -> bit-identical dot2 inputs -> absmax
// unchanged 0.0625). W1 is now fully on-chip: per half 64 AGPR pairs + 36
// VGPR pairs + 28 LDS pairs + fp32 edge rows. No per-step global traffic at
// all (only x, 8 floats/block/step). g_w1p16 + repack kernel deleted.
// Pair u = inps rows (9+2u, 10+2u), u in [0,252).
//   half0: AGPR u[0,64), LDS u[64,92), VGPR u[92,124)  (32 pairs, 8 groups)
//   half1: AGPR u[124,188), LDS u[188,216), VGPR u[216,252) (36 pairs, 9 groups)
// fp32 edge rows: {0..8} = x0..7 + s (half0), {513..520} = hx504..511 (half1).
// Structure: split-K, 1024 thr, 16 waves, 4/SIMD, 256 blocks, 3 barriers/step
// (R12/R15/R16 lineage -- the verified-safe staging).

constexpr int kN   = 256;
constexpr int kL   = 1024;
constexpr int kHin = 8;
constexpr int kHid = 512;
constexpr int kBlk = 1024;

constexpr int AG_P = 64;   // AGPR fp16-pairs per half
constexpr int LD_P = 28;   // LDS fp16-pairs per half (7 uint4 rows)
constexpr int VR_P = 36;   // arch-VGPR fp16-pairs per half (half0 uses 32)
constexpr int NCH0 = 8;    // VGPR chunks (4 pairs each), half0
constexpr int NCH1 = 9;    // VGPR chunks, half1

// pair-index bases (all multiples of 4 -> 16B-aligned uint4 access)
constexpr int A0P = 0,   L0P = 64,  S0P = 92;
constexpr int A1P = 124, L1P = 188, S1P = 216;
static_assert(A0P + AG_P == L0P, "");
static_assert(L0P + LD_P == S0P, "");
static_assert(S0P + 4 * NCH0 == A1P, "");
static_assert(A1P + AG_P == L1P, "");
static_assert(L1P + LD_P == S1P, "");
static_assert(S1P + 4 * NCH1 == 252, "");
static_assert(4 * NCH1 == VR_P, "half1 fills all VGPR pairs");

__device__ __forceinline__ unsigned pk2h_rne(float lo, float hi) {
  return (unsigned)__half_as_ushort(__float2half_rn(lo)) |
         ((unsigned)__half_as_ushort(__float2half_rn(hi)) << 16);
}

// d = a.lo*b.lo + a.hi*b.hi + c   (fp16 products exact in f32 accumulate)
__device__ __forceinline__ float dot2h(unsigned a, unsigned b, float c) {
  float d;
  asm("v_dot2_f32_f16 %0, %1, %2, %3" : "=v"(d) : "v"(a), "v"(b), "v"(c));
  return d;
}

__global__
__attribute__((amdgpu_flat_work_group_size(kBlk, kBlk)))
__attribute__((amdgpu_waves_per_eu(4, 4)))
void resrnn_fwd(const float* __restrict__ x, const float* __restrict__ W1,
                const float* __restrict__ b1, const float* __restrict__ W2,
                const float* __restrict__ b2, float* __restrict__ out) {
  // inps: [0..7]=x_t, [8]=unused, [9..520]=hx_{t-1} (fp32, canonical)
  __shared__ __align__(16) float inps[524];
  __shared__ uint4 wlds4[14][kHid];       // fp16 pair-weights, 4 pairs/uint4, 114.7 KB
  __shared__ float4 wedge4[4][kHid];      // fp32 rows {0-3},{4-7},{513-516},{517-520}
  __shared__ float wsrow[kHid];           // fp32 row 8 (s)
  __shared__ __align__(16) uint4 hx16q[63];  // fp16 hx pairs, uint4 view, 1 KB
  __shared__ float part[2][kHid];         // cross-half partials
  __shared__ __align__(16) float red[8];

  unsigned* const hx16 = reinterpret_cast<unsigned*>(hx16q);

  const int tid  = threadIdx.x;
  const int j    = tid & (kHid - 1);   // hidden column
  const int half = tid >> 9;           // K-half (wave-uniform)
  const int n    = blockIdx.x;         // batch element

  const float b2v = b2[0];
  const float w2j = W2[j];
  const float b1j = b1[j];

  float* const outp = out;
  float* const stor = out + (size_t)kN * kL;

  const float* xn = x + (size_t)n * kL * kHin;
  const float* const wj = W1 + j;      // column j, stride kHid

  // ---- one-time fill ----
  unsigned areg[AG_P];                 // 64 AGPR fp16 pairs (128 rows)
  const int apb = half ? A1P : A0P;
  #pragma unroll
  for (int g = 0; g < AG_P; ++g) {
    const int p = apb + g;
    const unsigned v = pk2h_rne(wj[(size_t)(9 + 2 * p) * kHid],
                                wj[(size_t)(10 + 2 * p) * kHid]);
    asm volatile("v_accvgpr_write_b32 %0, %1" : "=a"(areg[g]) : "v"(v));
  }
  // 36 arch-VGPR fp16 pairs (half0 fills 36 too -- last 4 unused, valid rows)
  unsigned sreg[VR_P];
  const int spb = half ? S1P : S0P;
  #pragma unroll
  for (int g = 0; g < VR_P; ++g) {
    const int p = spb + g;             // half0: 92..127 (124..127 unused but valid)
    sreg[g] = pk2h_rne(wj[(size_t)(9 + 2 * p) * kHid],
                       wj[(size_t)(10 + 2 * p) * kHid]);
  }
  #pragma unroll
  for (int g = 0; g < VR_P; ++g) asm volatile("" : "+v"(sreg[g]));

  const int lpb = half ? L1P : L0P;
  for (int k = 0; k < 7; ++k) {        // 7 uint4 weight rows per half
    uint4 wv;
    const int p = lpb + 4 * k;
    wv.x = pk2h_rne(wj[(size_t)(9 + 2 * (p + 0)) * kHid], wj[(size_t)(10 + 2 * (p + 0)) * kHid]);
    wv.y = pk2h_rne(wj[(size_t)(9 + 2 * (p + 1)) * kHid], wj[(size_t)(10 + 2 * (p + 1)) * kHid]);
    wv.z = pk2h_rne(wj[(size_t)(9 + 2 * (p + 2)) * kHid], wj[(size_t)(10 + 2 * (p + 2)) * kHid]);
    wv.w = pk2h_rne(wj[(size_t)(9 + 2 * (p + 3)) * kHid], wj[(size_t)(10 + 2 * (p + 3)) * kHid]);
    wlds4[half * 7 + k][j] = wv;
  }
  if (!half) {
    float4 wa, wb;
    wa.x = wj[0 * kHid]; wa.y = wj[1 * kHid]; wa.z = wj[2 * kHid]; wa.w = wj[3 * kHid];
    wb.x = wj[4 * kHid]; wb.y = wj[5 * kHid]; wb.z = wj[6 * kHid]; wb.w = wj[7 * kHid];
    wedge4[0][j] = wa; wedge4[1][j] = wb;
    wsrow[j] = wj[8 * kHid];
  } else {
    float4 wa, wb;
    wa.x = wj[(size_t)513 * kHid]; wa.y = wj[(size_t)514 * kHid];
    wa.z = wj[(size_t)515 * kHid]; wa.w = wj[(size_t)516 * kHid];
    wb.x = wj[(size_t)517 * kHid]; wb.y = wj[(size_t)518 * kHid];
    wb.z = wj[(size_t)519 * kHid]; wb.w = wj[(size_t)520 * kHid];
    wedge4[2][j] = wa; wedge4[3][j] = wb;
  }

  // ---- init: hx = 0, s_0 = x_0[0] ----
  float s = xn[0];
  if (!half) inps[9 + j] = 0.f;
  if (half && j < kHin) inps[j] = xn[j];
  if (tid < 252) hx16[tid] = 0u;
  if (tid == 0) stor[(size_t)n * kL] = s;
  __syncthreads();

  for (int t = 0; t < kL; ++t) {
    float a0 = half ? 0.f : b1j;   // dot2 chain A
    float c0 = 0.f;                // dot2 chain B

    // ---- AGPR phase: 8 groups x 8 pairs, hx via aligned uint4 ----
    const int aqb = half ? (A1P / 4) : (A0P / 4);
    #pragma unroll
    for (int g = 0; g < 8; ++g) {
      const uint4 qa = hx16q[aqb + 2 * g];
      const uint4 qb = hx16q[aqb + 2 * g + 1];
      unsigned w0, w1, w2, w3, w4, w5, w6, w7;
      asm volatile(
          "v_accvgpr_read_b32 %0, %8\n\t"
          "v_accvgpr_read_b32 %1, %9\n\t"
          "v_accvgpr_read_b32 %2, %10\n\t"
          "v_accvgpr_read_b32 %3, %11\n\t"
          "v_accvgpr_read_b32 %4, %12\n\t"
          "v_accvgpr_read_b32 %5, %13\n\t"
          "v_accvgpr_read_b32 %6, %14\n\t"
          "v_accvgpr_read_b32 %7, %15"
          : "=v"(w0), "=v"(w1), "=v"(w2), "=v"(w3),
            "=v"(w4), "=v"(w5), "=v"(w6), "=v"(w7)
          : "a"(areg[8 * g + 0]), "a"(areg[8 * g + 1]),
            "a"(areg[8 * g + 2]), "a"(areg[8 * g + 3]),
            "a"(areg[8 * g + 4]), "a"(areg[8 * g + 5]),
            "a"(areg[8 * g + 6]), "a"(areg[8 * g + 7]));
      a0 = dot2h(qa.x, w0, a0); c0 = dot2h(qa.y, w1, c0);
      a0 = dot2h(qa.z, w2, a0); c0 = dot2h(qa.w, w3, c0);
      a0 = dot2h(qb.x, w4, a0); c0 = dot2h(qb.y, w5, c0);
      a0 = dot2h(qb.z, w6, a0); c0 = dot2h(qb.w, w7, c0);
    }

    // ---- LDS phase: 7 x (uint4 hx + uint4 weights) = 28 pairs ----
    const int lqb = half ? (L1P / 4) : (L0P / 4);
    #pragma unroll
    for (int k = 0; k < 7; ++k) {
      const uint4 hq = hx16q[lqb + k];
      const uint4 wq = wlds4[half * 7 + k][j];
      a0 = dot2h(hq.x, wq.x, a0); c0 = dot2h(hq.y, wq.y, c0);
      a0 = dot2h(hq.z, wq.z, a0); c0 = dot2h(hq.w, wq.w, c0);
    }

    // ---- VGPR phase (was streamed): pinned sreg pairs, static indices ----
    if (!half) {
      #pragma unroll
      for (int c = 0; c < NCH0; ++c) {
        const uint4 hq = hx16q[S0P / 4 + c];
        a0 = dot2h(hq.x, sreg[4 * c + 0], a0); c0 = dot2h(hq.y, sreg[4 * c + 1], c0);
        a0 = dot2h(hq.z, sreg[4 * c + 2], a0); c0 = dot2h(hq.w, sreg[4 * c + 3], c0);
      }
      // ---- fp32 edge rows 0..8: x0..7 + s ----
      const float4 x03 = *reinterpret_cast<const float4*>(&inps[0]);
      const float4 x47 = *reinterpret_cast<const float4*>(&inps[4]);
      const float4 wa = wedge4[0][j];
      const float4 wb = wedge4[1][j];
      a0 = fmaf(x03.x, wa.x, a0); c0 = fmaf(x03.y, wa.y, c0);
      a0 = fmaf(x03.z, wa.z, a0); c0 = fmaf(x03.w, wa.w, c0);
      a0 = fmaf(x47.x, wb.x, a0); c0 = fmaf(x47.y, wb.y, c0);
      a0 = fmaf(x47.z, wb.z, a0); c0 = fmaf(x47.w, wb.w, c0);
      a0 = fmaf(s, wsrow[j], a0);
    } else {
      #pragma unroll
      for (int c = 0; c < NCH1; ++c) {
        const uint4 hq = hx16q[S1P / 4 + c];
        a0 = dot2h(hq.x, sreg[4 * c + 0], a0); c0 = dot2h(hq.y, sreg[4 * c + 1], c0);
        a0 = dot2h(hq.z, sreg[4 * c + 2], a0); c0 = dot2h(hq.w, sreg[4 * c + 3], c0);
      }
      // ---- fp32 edge rows 513..520 (hx 504..511) ----
      const float v0 = inps[513];
      const float2 v12 = *reinterpret_cast<const float2*>(&inps[514]);
      const float4 v36 = *reinterpret_cast<const float4*>(&inps[516]);
      const float v7 = inps[520];
      const float4 wa = wedge4[2][j];
      const float4 wb = wedge4[3][j];
      a0 = fmaf(v0, wa.x, a0);    c0 = fmaf(v12.x, wa.y, c0);
      a0 = fmaf(v12.y, wa.z, a0); c0 = fmaf(v36.x, wa.w, c0);
      a0 = fmaf(v36.y, wb.x, a0); c0 = fmaf(v36.z, wb.y, c0);
      a0 = fmaf(v36.w, wb.z, a0); c0 = fmaf(v7, wb.w, c0);
    }

    part[half][j] = a0 + c0;
    __syncthreads();  // barrier 2: partials ready; all hx16q/inps reads done

    const float h = tanhf(part[0][j] + part[1][j]);

    // stage next-step inputs that don't depend on o
    if (!half) inps[9 + j] = h;
    const float* xr = xn + (size_t)(t + 1) * kHin;
    if (t + 1 < kL && half && j < kHin) inps[j] = xr[j];

    // ---- out = h . W2 + b2 : half0 waves shuffle-reduce ----
    if (!half) {
      float p = h * w2j;
      #pragma unroll
      for (int off = 32; off > 0; off >>= 1) p += __shfl_down(p, off, 64);
      if ((tid & 63) == 0) red[tid >> 6] = p;
    }
    __syncthreads();  // barrier 3: red ready; h/x fully staged in inps

    // restage hx16 pairs u = 0..251 from the (next-step) inps
    if (tid < 252) {
      hx16[tid] = pk2h_rne(inps[9 + 2 * tid], inps[10 + 2 * tid]);
    }

    const float4 r0 = *reinterpret_cast<const float4*>(&red[0]);
    const float4 r1 = *reinterpret_cast<const float4*>(&red[4]);
    const float o = (((r0.x + r0.y) + (r0.z + r0.w)) +
                     ((r1.x + r1.y) + (r1.z + r1.w))) + b2v;  // same in all threads
    if (tid == 0) outp[(size_t)n * kL + t] = o;

    if (t + 1 < kL) {
      s += xr[0] - o;  // private s, replicated identically across all threads
      if (tid == 0) stor[(size_t)n * kL + t + 1] = s;
    }
    __syncthreads();  // barrier 1 (loop top): next-step inps + hx16 staged
  }
}

extern "C" void kernel_launch(void* const* d_in, const int* in_sizes, int n_in,
                              void* d_out, int out_size, void* d_ws, size_t ws_size,
                              hipStream_t stream) {
  const float* x  = (const float*)d_in[0];
  const float* W1 = (const float*)d_in[1];
  const float* b1 = (const float*)d_in[2];
  const float* W2 = (const float*)d_in[3];
  const float* b2 = (const float*)d_in[4];
  float* out = (float*)d_out;

  dim3 grid(kN);          // 256 blocks, 1 batch each, all 256 CUs
  dim3 block(kBlk);       // 1024 threads = 16 waves = 4 waves/SIMD
  hipLaunchKernelGGL(resrnn_fwd, grid, block, 0, stream, x, W1, b1, W2, b2, out);
}

// Round 19
// 2863.999 us; speedup vs baseline: 1.2415x; 1.2415x over previous
//
#include <hip/hip_runtime.h>
#include <hip/hip_fp16.h>
#include <math.h>

// resRNN forward: N=256, L=1024, inp=521 (=8 x + 1 storage + 512 hx), HID=512, OUT=1.
// Round 19: restore R16 (best verified: 2.945 ms, absmax 0.0625). R18 closed
// the AGPR-direct-operand branch (assembler: VOP3P cannot take AGPR src) and
// R17 closed full-residency (RF already full: 64 arch + 64 accum = 128/wave).
// Only edit vs R16: tanhf sunk into the half0 branch (h is consumed only
// there) -- semantics identical.
// Step model at this point: ~6.9K cyc = L2-stream 3.4K (131 KB/step/CU at the
// measured ~38.4 B/cyc/CU ceiling; residency maxed) ?? VALU ~4.4K busy,
// partially overlapped. All levers tried: <fp16 breaks accuracy, fewer
// barriers diverged (R13/14), more waves neutral (R9), residency capacity-
// bound (R17). Structural floor for this algorithm shape.
// Pair u = inps rows (9+2u, 10+2u), u in [0,252).
//   half0: AGPR u[0,64), LDS u[64,92), stream u[92,124)  (8 uint4 chunks)
//   half1: AGPR u[124,188), LDS u[188,216), stream u[216,252) (9 chunks)
// fp32 edge rows: {0..8} = x0..7 + s (half0), {513..520} = hx504..511 (half1).
// Structure: split-K, 1024 thr, 16 waves, 4/SIMD, 256 blocks, 3 barriers/step.

constexpr int kN   = 256;
constexpr int kL   = 1024;
constexpr int kHin = 8;
constexpr int kHid = 512;
constexpr int kBlk = 1024;

constexpr int AG_P = 64;   // AGPR fp16-pairs per half
constexpr int LD_P = 28;   // LDS fp16-pairs per half (7 uint4 rows)
constexpr int NCH0 = 8;    // streamed uint4 chunks (4 pairs each), half0
constexpr int NCH1 = 9;    // streamed chunks, half1
constexpr int NCHT = NCH0 + NCH1;

// pair-index bases (all multiples of 4 -> 16B-aligned uint4 access)
constexpr int A0P = 0,   L0P = 64,  S0P = 92;
constexpr int A1P = 124, L1P = 188, S1P = 216;
static_assert(A0P + AG_P == L0P, "");
static_assert(L0P + LD_P == S0P, "");
static_assert(S0P + 4 * NCH0 == A1P, "");
static_assert(A1P + AG_P == L1P, "");
static_assert(L1P + LD_P == S1P, "");
static_assert(S1P + 4 * NCH1 == 252, "");

// Streamed fp16 weights: g_w1p16[c*512 + j] = pairs p0(c)..p0(c)+3 of column j;
// dword = fp16(W1[9+2p][j]) | fp16(W1[10+2p][j]) << 16 (rne).
__device__ __align__(16) uint4 g_w1p16[NCHT * kHid];

__device__ __forceinline__ unsigned pk2h_rne(float lo, float hi) {
  return (unsigned)__half_as_ushort(__float2half_rn(lo)) |
         ((unsigned)__half_as_ushort(__float2half_rn(hi)) << 16);
}

// d = a.lo*b.lo + a.hi*b.hi + c   (fp16 products exact in f32 accumulate)
__device__ __forceinline__ float dot2h(unsigned a, unsigned b, float c) {
  float d;
  asm("v_dot2_f32_f16 %0, %1, %2, %3" : "=v"(d) : "v"(a), "v"(b), "v"(c));
  return d;
}

__global__ void repack_w1(const float* __restrict__ W1) {
  const int idx = blockIdx.x * 256 + threadIdx.x;
  if (idx >= NCHT * kHid) return;
  const int c = idx >> 9;
  const int j = idx & (kHid - 1);
  const int p0 = (c < NCH0) ? (S0P + 4 * c) : (S1P + 4 * (c - NCH0));
  uint4 pk;
  pk.x = pk2h_rne(W1[(size_t)(9 + 2 * (p0 + 0)) * kHid + j],
                  W1[(size_t)(10 + 2 * (p0 + 0)) * kHid + j]);
  pk.y = pk2h_rne(W1[(size_t)(9 + 2 * (p0 + 1)) * kHid + j],
                  W1[(size_t)(10 + 2 * (p0 + 1)) * kHid + j]);
  pk.z = pk2h_rne(W1[(size_t)(9 + 2 * (p0 + 2)) * kHid + j],
                  W1[(size_t)(10 + 2 * (p0 + 2)) * kHid + j]);
  pk.w = pk2h_rne(W1[(size_t)(9 + 2 * (p0 + 3)) * kHid + j],
                  W1[(size_t)(10 + 2 * (p0 + 3)) * kHid + j]);
  g_w1p16[idx] = pk;
}

__global__
__attribute__((amdgpu_flat_work_group_size(kBlk, kBlk)))
__attribute__((amdgpu_waves_per_eu(4, 4)))
void resrnn_fwd(const float* __restrict__ x, const float* __restrict__ W1,
                const float* __restrict__ b1, const float* __restrict__ W2,
                const float* __restrict__ b2, float* __restrict__ out) {
  // inps: [0..7]=x_t, [8]=unused, [9..520]=hx_{t-1} (fp32, canonical)
  __shared__ __align__(16) float inps[524];
  __shared__ uint4 wlds4[14][kHid];       // fp16 pair-weights, 4 pairs/uint4, 114.7 KB
  __shared__ float4 wedge4[4][kHid];      // fp32 rows {0-3},{4-7},{513-516},{517-520}
  __shared__ float wsrow[kHid];           // fp32 row 8 (s)
  __shared__ __align__(16) uint4 hx16q[63];  // fp16 hx pairs, uint4 view, 1 KB
  __shared__ float part[2][kHid];         // cross-half partials
  __shared__ __align__(16) float red[8];

  unsigned* const hx16 = reinterpret_cast<unsigned*>(hx16q);

  const int tid  = threadIdx.x;
  const int j    = tid & (kHid - 1);   // hidden column
  const int half = tid >> 9;           // K-half (wave-uniform)
  const int n    = blockIdx.x;         // batch element

  const float b2v = b2[0];
  const float w2j = W2[j];
  const float b1j = b1[j];

  float* const outp = out;
  float* const stor = out + (size_t)kN * kL;

  const float* xn = x + (size_t)n * kL * kHin;
  const float* const wj = W1 + j;      // column j, stride kHid

  // ---- one-time fill ----
  unsigned areg[AG_P];                 // 64 AGPR fp16 pairs (128 rows)
  const int apb = half ? A1P : A0P;
  #pragma unroll
  for (int g = 0; g < AG_P; ++g) {
    const int p = apb + g;
    const unsigned v = pk2h_rne(wj[(size_t)(9 + 2 * p) * kHid],
                                wj[(size_t)(10 + 2 * p) * kHid]);
    asm volatile("v_accvgpr_write_b32 %0, %1" : "=a"(areg[g]) : "v"(v));
  }
  const int lpb = half ? L1P : L0P;
  for (int k = 0; k < 7; ++k) {        // 7 uint4 weight rows per half
    uint4 wv;
    const int p = lpb + 4 * k;
    wv.x = pk2h_rne(wj[(size_t)(9 + 2 * (p + 0)) * kHid], wj[(size_t)(10 + 2 * (p + 0)) * kHid]);
    wv.y = pk2h_rne(wj[(size_t)(9 + 2 * (p + 1)) * kHid], wj[(size_t)(10 + 2 * (p + 1)) * kHid]);
    wv.z = pk2h_rne(wj[(size_t)(9 + 2 * (p + 2)) * kHid], wj[(size_t)(10 + 2 * (p + 2)) * kHid]);
    wv.w = pk2h_rne(wj[(size_t)(9 + 2 * (p + 3)) * kHid], wj[(size_t)(10 + 2 * (p + 3)) * kHid]);
    wlds4[half * 7 + k][j] = wv;
  }
  if (!half) {
    float4 wa, wb;
    wa.x = wj[0 * kHid]; wa.y = wj[1 * kHid]; wa.z = wj[2 * kHid]; wa.w = wj[3 * kHid];
    wb.x = wj[4 * kHid]; wb.y = wj[5 * kHid]; wb.z = wj[6 * kHid]; wb.w = wj[7 * kHid];
    wedge4[0][j] = wa; wedge4[1][j] = wb;
    wsrow[j] = wj[8 * kHid];
  } else {
    float4 wa, wb;
    wa.x = wj[(size_t)513 * kHid]; wa.y = wj[(size_t)514 * kHid];
    wa.z = wj[(size_t)515 * kHid]; wa.w = wj[(size_t)516 * kHid];
    wb.x = wj[(size_t)517 * kHid]; wb.y = wj[(size_t)518 * kHid];
    wb.z = wj[(size_t)519 * kHid]; wb.w = wj[(size_t)520 * kHid];
    wedge4[2][j] = wa; wedge4[3][j] = wb;
  }

  const uint4* const wpk = g_w1p16 + (half ? (size_t)NCH0 * kHid : 0) + j;

  // ---- init: hx = 0, s_0 = x_0[0] ----
  float s = xn[0];
  if (!half) inps[9 + j] = 0.f;
  if (half && j < kHin) inps[j] = xn[j];
  if (tid < 252) hx16[tid] = 0u;
  if (tid == 0) stor[(size_t)n * kL] = s;
  __syncthreads();

  for (int t = 0; t < kL; ++t) {
    float a0 = half ? 0.f : b1j;   // dot2 chain A
    float c0 = 0.f;                // dot2 chain B

    // ---- AGPR phase: 8 groups x 8 pairs, hx via aligned uint4 ----
    const int aqb = half ? (A1P / 4) : (A0P / 4);
    #pragma unroll
    for (int g = 0; g < 8; ++g) {
      const uint4 qa = hx16q[aqb + 2 * g];
      const uint4 qb = hx16q[aqb + 2 * g + 1];
      unsigned w0, w1, w2, w3, w4, w5, w6, w7;
      asm volatile(
          "v_accvgpr_read_b32 %0, %8\n\t"
          "v_accvgpr_read_b32 %1, %9\n\t"
          "v_accvgpr_read_b32 %2, %10\n\t"
          "v_accvgpr_read_b32 %3, %11\n\t"
          "v_accvgpr_read_b32 %4, %12\n\t"
          "v_accvgpr_read_b32 %5, %13\n\t"
          "v_accvgpr_read_b32 %6, %14\n\t"
          "v_accvgpr_read_b32 %7, %15"
          : "=v"(w0), "=v"(w1), "=v"(w2), "=v"(w3),
            "=v"(w4), "=v"(w5), "=v"(w6), "=v"(w7)
          : "a"(areg[8 * g + 0]), "a"(areg[8 * g + 1]),
            "a"(areg[8 * g + 2]), "a"(areg[8 * g + 3]),
            "a"(areg[8 * g + 4]), "a"(areg[8 * g + 5]),
            "a"(areg[8 * g + 6]), "a"(areg[8 * g + 7]));
      a0 = dot2h(qa.x, w0, a0); c0 = dot2h(qa.y, w1, c0);
      a0 = dot2h(qa.z, w2, a0); c0 = dot2h(qa.w, w3, c0);
      a0 = dot2h(qb.x, w4, a0); c0 = dot2h(qb.y, w5, c0);
      a0 = dot2h(qb.z, w6, a0); c0 = dot2h(qb.w, w7, c0);
    }

    // ---- LDS phase: 7 x (uint4 hx + uint4 weights) = 28 pairs ----
    const int lqb = half ? (L1P / 4) : (L0P / 4);
    #pragma unroll
    for (int k = 0; k < 7; ++k) {
      const uint4 hq = hx16q[lqb + k];
      const uint4 wq = wlds4[half * 7 + k][j];
      a0 = dot2h(hq.x, wq.x, a0); c0 = dot2h(hq.y, wq.y, c0);
      a0 = dot2h(hq.z, wq.z, a0); c0 = dot2h(hq.w, wq.w, c0);
    }

    // ---- streamed phase: uint4 hx + global uint4 weights ----
    if (!half) {
      #pragma unroll 4
      for (int c = 0; c < NCH0; ++c) {
        const uint4 pk = wpk[(size_t)c * kHid];
        const uint4 hq = hx16q[S0P / 4 + c];
        a0 = dot2h(hq.x, pk.x, a0); c0 = dot2h(hq.y, pk.y, c0);
        a0 = dot2h(hq.z, pk.z, a0); c0 = dot2h(hq.w, pk.w, c0);
      }
      // ---- fp32 edge rows 0..8: x0..7 + s ----
      const float4 x03 = *reinterpret_cast<const float4*>(&inps[0]);
      const float4 x47 = *reinterpret_cast<const float4*>(&inps[4]);
      const float4 wa = wedge4[0][j];
      const float4 wb = wedge4[1][j];
      a0 = fmaf(x03.x, wa.x, a0); c0 = fmaf(x03.y, wa.y, c0);
      a0 = fmaf(x03.z, wa.z, a0); c0 = fmaf(x03.w, wa.w, c0);
      a0 = fmaf(x47.x, wb.x, a0); c0 = fmaf(x47.y, wb.y, c0);
      a0 = fmaf(x47.z, wb.z, a0); c0 = fmaf(x47.w, wb.w, c0);
      a0 = fmaf(s, wsrow[j], a0);
    } else {
      #pragma unroll 3
      for (int c = 0; c < NCH1; ++c) {
        const uint4 pk = wpk[(size_t)c * kHid];
        const uint4 hq = hx16q[S1P / 4 + c];
        a0 = dot2h(hq.x, pk.x, a0); c0 = dot2h(hq.y, pk.y, c0);
        a0 = dot2h(hq.z, pk.z, a0); c0 = dot2h(hq.w, pk.w, c0);
      }
      // ---- fp32 edge rows 513..520 (hx 504..511) ----
      const float v0 = inps[513];
      const float2 v12 = *reinterpret_cast<const float2*>(&inps[514]);
      const float4 v36 = *reinterpret_cast<const float4*>(&inps[516]);
      const float v7 = inps[520];
      const float4 wa = wedge4[2][j];
      const float4 wb = wedge4[3][j];
      a0 = fmaf(v0, wa.x, a0);    c0 = fmaf(v12.x, wa.y, c0);
      a0 = fmaf(v12.y, wa.z, a0); c0 = fmaf(v36.x, wa.w, c0);
      a0 = fmaf(v36.y, wb.x, a0); c0 = fmaf(v36.z, wb.y, c0);
      a0 = fmaf(v36.w, wb.z, a0); c0 = fmaf(v7, wb.w, c0);
    }

    part[half][j] = a0 + c0;
    __syncthreads();  // barrier 2: partials ready; all hx16q/inps reads done

    const float* xr = xn + (size_t)(t + 1) * kHin;
    if (!half) {
      // tanh computed by half0 only (h is consumed only here)
      const float h = tanhf(part[0][j] + part[1][j]);
      inps[9 + j] = h;
      // out-projection partial: wave shuffle reduce
      float p = h * w2j;
      #pragma unroll
      for (int off = 32; off > 0; off >>= 1) p += __shfl_down(p, off, 64);
      if ((tid & 63) == 0) red[tid >> 6] = p;
    } else if (j < kHin && t + 1 < kL) {
      inps[j] = xr[j];  // stage next-step x
    }
    __syncthreads();  // barrier 3: red ready; h/x fully staged in inps

    // restage hx16 pairs u = 0..251 from the (next-step) inps
    if (tid < 252) {
      hx16[tid] = pk2h_rne(inps[9 + 2 * tid], inps[10 + 2 * tid]);
    }

    const float4 r0 = *reinterpret_cast<const float4*>(&red[0]);
    const float4 r1 = *reinterpret_cast<const float4*>(&red[4]);
    const float o = (((r0.x + r0.y) + (r0.z + r0.w)) +
                     ((r1.x + r1.y) + (r1.z + r1.w))) + b2v;  // same in all threads
    if (tid == 0) outp[(size_t)n * kL + t] = o;

    if (t + 1 < kL) {
      s += xr[0] - o;  // private s, replicated identically across all threads
      if (tid == 0) stor[(size_t)n * kL + t + 1] = s;
    }
    __syncthreads();  // barrier 1 (loop top): next-step inps + hx16 staged
  }
}

extern "C" void kernel_launch(void* const* d_in, const int* in_sizes, int n_in,
                              void* d_out, int out_size, void* d_ws, size_t ws_size,
                              hipStream_t stream) {
  const float* x  = (const float*)d_in[0];
  const float* W1 = (const float*)d_in[1];
  const float* b1 = (const float*)d_in[2];
  const float* W2 = (const float*)d_in[3];
  const float* b2 = (const float*)d_in[4];
  float* out = (float*)d_out;

  // one-time (per launch) repack of streamed W1 rows into packed fp16 form
  {
    const int total = NCHT * kHid;                // 8704
    dim3 g((total + 255) / 256), b(256);
    hipLaunchKernelGGL(repack_w1, g, b, 0, stream, W1);
  }

  dim3 grid(kN);          // 256 blocks, 1 batch each, all 256 CUs
  dim3 block(kBlk);       // 1024 threads = 16 waves = 4 waves/SIMD
  hipLaunchKernelGGL(resrnn_fwd, grid, block, 0, stream, x, W1, b1, W2, b2, out);
}